// Round 2
// baseline (266.915 us; speedup 1.0000x reference)
//
#include <hip/hip_runtime.h>
#include <math.h>

#define N_BOX 4096
#define B_IMG 16
#define MAXDET 100
#define MINSZ 25.0f
#define IOUT 0.3f

// IoU with the reference's exact op order:
//   inter / (((ai + aj) - inter) + 1e-9)
// fp contract OFF so hipcc doesn't fuse wx*wy into the subtract (XLA doesn't).
__device__ __forceinline__ float iou_f(float ax1, float ay1, float ax2, float ay2, float aarea,
                                       float bx1, float by1, float bx2, float by2, float barea) {
#pragma clang fp contract(off)
    float lx = fmaxf(ax1, bx1);
    float ly = fmaxf(ay1, by1);
    float rx = fminf(ax2, bx2);
    float ry = fminf(ay2, by2);
    float wx = fmaxf(rx - lx, 0.0f);
    float wy = fmaxf(ry - ly, 0.0f);
    float inter = wx * wy;
    float denom = ((aarea + barea) - inter) + 1e-9f;
    return inter / denom;
}

// --- Kernel 1: stable rank (argsort of -key, ties by index) + scatter to sorted order ---
// grid: B_IMG*16 blocks, 256 threads. Block (b,g) handles originals g*256..g*256+255.
__global__ __launch_bounds__(256) void rank_scatter_kernel(
        const float* __restrict__ boxes, const float* __restrict__ scores,
        float4* __restrict__ sboxes, float* __restrict__ skeys) {
    __shared__ __align__(16) float key[N_BOX];
    int b = blockIdx.x >> 4;
    int g = blockIdx.x & 15;
    int t = threadIdx.x;
    const float4* bb = (const float4*)(boxes + (size_t)b * N_BOX * 4);
    const float* ss = scores + (size_t)b * N_BOX;

    // build keys: valid ? score : -inf
#pragma unroll
    for (int p = 0; p < 16; ++p) {
        int j = t + 256 * p;
        float4 bx = bb[j];
        float w = bx.z - bx.x;
        float h = bx.w - bx.y;
        float k = ((w >= MINSZ) && (h >= MINSZ)) ? ss[j] : -INFINITY;
        key[j] = k;
    }
    __syncthreads();

    int i = g * 256 + t;
    float si = key[i];
    int rank = 0;
    const float4* k4 = (const float4*)key;
    for (int j4 = 0; j4 < N_BOX / 4; ++j4) {
        float4 s4 = k4[j4];
        int j = j4 * 4;
        rank += (s4.x > si || (s4.x == si && (j + 0) < i)) ? 1 : 0;
        rank += (s4.y > si || (s4.y == si && (j + 1) < i)) ? 1 : 0;
        rank += (s4.z > si || (s4.z == si && (j + 2) < i)) ? 1 : 0;
        rank += (s4.w > si || (s4.w == si && (j + 3) < i)) ? 1 : 0;
    }
    float4 mybox = bb[i];
    sboxes[(size_t)b * N_BOX + rank] = mybox;
    skeys[(size_t)b * N_BOX + rank] = si;
}

// --- Kernel 2: greedy NMS over sorted boxes + emit first MAXDET kept ---
// grid: B_IMG blocks, 1024 threads. Thread t holds sorted boxes t+1024k (k=0..3)
// in registers. Chunks of 64 boxes: chunk c owned by wave c%16 at slot k=c/16.
__global__ __launch_bounds__(1024) void nms_kernel(
        const float4* __restrict__ sboxes, const float* __restrict__ skeys,
        float* __restrict__ out) {
    __shared__ float ck[64][5];          // this chunk's final-kept boxes (+area)
    __shared__ int ckn;                  // count of kept in chunk
    __shared__ int keptTotal;            // running kept count (prefix-final)
    __shared__ float outBuf[MAXDET][4];  // first MAXDET kept boxes, in order
    int b = blockIdx.x;
    int t = threadIdx.x;
    int w = t >> 6, l = t & 63;

    float x1[4], y1[4], x2[4], y2[4], ar[4];
    bool keep[4];
#pragma unroll
    for (int k = 0; k < 4; ++k) {
        int idx = t + 1024 * k;
        float4 bx = sboxes[(size_t)b * N_BOX + idx];
        x1[k] = bx.x; y1[k] = bx.y; x2[k] = bx.z; y2[k] = bx.w;
        {
#pragma clang fp contract(off)
            ar[k] = (bx.z - bx.x) * (bx.w - bx.y);
        }
        keep[k] = (skeys[(size_t)b * N_BOX + idx] != -INFINITY);
    }
    if (t == 0) keptTotal = 0;
    __syncthreads();

    for (int c = 0; c < 64; ++c) {
        int kk = c >> 4;
        if (w == (c & 15)) {
            // Phase A: intra-chunk greedy NMS, serial over kept bits (ascending = greedy order)
            unsigned long long m = __ballot(keep[kk]);
            unsigned long long mm = m;
            while (mm) {
                int i = __ffsll(mm) - 1;
                float bx1 = __shfl(x1[kk], i);
                float by1 = __shfl(y1[kk], i);
                float bx2 = __shfl(x2[kk], i);
                float by2 = __shfl(y2[kk], i);
                float ba  = __shfl(ar[kk], i);
                float v = iou_f(bx1, by1, bx2, by2, ba, x1[kk], y1[kk], x2[kk], y2[kk], ar[kk]);
                bool sup = (l > i) && (v > IOUT) && ((m >> l) & 1ull);
                unsigned long long sm = __ballot(sup);
                m &= ~sm;
                mm &= ~(1ull << i);
                mm &= m;
            }
            keep[kk] = (m >> l) & 1ull;
            int cnt = __popcll(m);
            int base = keptTotal;  // uniform read; updated below by lane 0
            int pos = __popcll(m & ((1ull << l) - 1ull));
            if (keep[kk]) {
                ck[pos][0] = x1[kk]; ck[pos][1] = y1[kk];
                ck[pos][2] = x2[kk]; ck[pos][3] = y2[kk]; ck[pos][4] = ar[kk];
                int op = base + pos;
                if (op < MAXDET) {
                    outBuf[op][0] = x1[kk]; outBuf[op][1] = y1[kk];
                    outBuf[op][2] = x2[kk]; outBuf[op][3] = y2[kk];
                }
            }
            if (l == 0) { ckn = cnt; keptTotal = base + cnt; }
        }
        __syncthreads();
        // kept statuses are final for all indices <= chunk end; once we have
        // MAXDET of them the rest can't change the output.
        if (keptTotal >= MAXDET || c == 63) break;
        // Phase B: suppress later boxes against this chunk's kept list
        int n = ckn;
        int chunkEnd = c * 64 + 63;
#pragma unroll
        for (int k = 0; k < 4; ++k) {
            int idx = t + 1024 * k;
            if (idx > chunkEnd && keep[k]) {
                for (int q = 0; q < n; ++q) {
                    float v = iou_f(ck[q][0], ck[q][1], ck[q][2], ck[q][3], ck[q][4],
                                    x1[k], y1[k], x2[k], y2[k], ar[k]);
                    if (v > IOUT) keep[k] = false;
                }
            }
        }
        __syncthreads();
    }
    __syncthreads();

    int tot = keptTotal < MAXDET ? keptTotal : MAXDET;
    if (t < MAXDET) {
        float* row = out + ((size_t)b * MAXDET + t) * 5;
        if (t < tot) {
            row[0] = (float)b;
            row[1] = outBuf[t][0]; row[2] = outBuf[t][1];
            row[3] = outBuf[t][2]; row[4] = outBuf[t][3];
        } else {
            row[0] = -1.0f;
            row[1] = 0.0f; row[2] = 0.0f; row[3] = 0.0f; row[4] = 0.0f;
        }
    }
}

extern "C" void kernel_launch(void* const* d_in, const int* in_sizes, int n_in,
                              void* d_out, int out_size, void* d_ws, size_t ws_size,
                              hipStream_t stream) {
    const float* boxes  = (const float*)d_in[0];   // [16,4096,4] f32
    const float* scores = (const float*)d_in[1];   // [16,4096] f32
    float* out = (float*)d_out;                    // [16,100,5] f32

    // workspace layout: sorted boxes (AoS float4) then sorted keys
    float4* sboxes = (float4*)d_ws;                                   // 1 MiB
    float*  skeys  = (float*)((char*)d_ws + (size_t)B_IMG * N_BOX * sizeof(float4)); // 256 KiB

    rank_scatter_kernel<<<B_IMG * 16, 256, 0, stream>>>(boxes, scores, sboxes, skeys);
    nms_kernel<<<B_IMG, 1024, 0, stream>>>(sboxes, skeys, out);
}

// Round 5
// 142.608 us; speedup vs baseline: 1.8717x; 1.8717x over previous
//
#include <hip/hip_runtime.h>
#include <math.h>

#define N_BOX 4096
#define B_IMG 16
#define MAXDET 100
#define MINSZ 25.0f
#define IOUT 0.3f
#define IG 16   // i-groups of 256 per image
#define JG 4    // j-groups of 1024 per image

// IoU with the reference's exact op order:
//   inter / (((ai + aj) - inter) + 1e-9)
// fp contract OFF so hipcc doesn't fuse wx*wy into the subtract (XLA doesn't).
__device__ __forceinline__ float iou_f(float ax1, float ay1, float ax2, float ay2, float aarea,
                                       float bx1, float by1, float bx2, float by2, float barea) {
#pragma clang fp contract(off)
    float lx = fmaxf(ax1, bx1);
    float ly = fmaxf(ay1, by1);
    float rx = fminf(ax2, bx2);
    float ry = fminf(ay2, by2);
    float wx = fmaxf(rx - lx, 0.0f);
    float wy = fmaxf(ry - ly, 0.0f);
    float inter = wx * wy;
    float denom = ((aarea + barea) - inter) + 1e-9f;
    return inter / denom;
}

// --- Kernel A: keys = valid ? score : -inf ---
__global__ __launch_bounds__(256) void key_kernel(
        const float4* __restrict__ boxes, const float* __restrict__ scores,
        float* __restrict__ keyArr) {
    int idx = blockIdx.x * 256 + threadIdx.x;   // b*N + i, 0..65535
    float4 bx = boxes[idx];
    float w = bx.z - bx.x;
    float h = bx.w - bx.y;
    keyArr[idx] = ((w >= MINSZ) && (h >= MINSZ)) ? scores[idx] : -INFINITY;
}

// --- Kernel B: partial stable ranks (descending key, ties by ascending index) ---
// grid: B_IMG*IG*JG = 1024 blocks x 256 threads -> 4 blocks/CU, 16 waves/CU.
// Block (b, ig, jg): threads own i = ig*256+t, scan j in [jg*1024, jg*1024+1024).
__global__ __launch_bounds__(256) void partial_rank_kernel(
        const float* __restrict__ keyArr, unsigned short* __restrict__ part) {
    int blk = blockIdx.x;
    int jg = blk & (JG - 1);
    int ig = (blk >> 2) & (IG - 1);
    int b  = blk >> 6;                 // JG*IG = 64
    int t = threadIdx.x;
    int i = ig * 256 + t;
    float si = keyArr[b * N_BOX + i];
    const float4* k4 = (const float4*)(keyArr + b * N_BOX + jg * 1024);
    int jbase = jg * 1024;
    int r = 0;
#pragma unroll 4
    for (int j4 = 0; j4 < 256; ++j4) {
        float4 s4 = k4[j4];            // wave-uniform address -> broadcast/SMEM
        int j = jbase + j4 * 4;
        r += (s4.x > si || (s4.x == si && (j + 0) < i)) ? 1 : 0;
        r += (s4.y > si || (s4.y == si && (j + 1) < i)) ? 1 : 0;
        r += (s4.z > si || (s4.z == si && (j + 2) < i)) ? 1 : 0;
        r += (s4.w > si || (s4.w == si && (j + 3) < i)) ? 1 : 0;
    }
    part[(b * JG + jg) * N_BOX + i] = (unsigned short)r;
}

// --- Kernel C: sum partials -> rank, scatter box+key to sorted order ---
__global__ __launch_bounds__(256) void scatter_kernel(
        const float4* __restrict__ boxes, const float* __restrict__ keyArr,
        const unsigned short* __restrict__ part,
        float4* __restrict__ sboxes, float* __restrict__ skeys) {
    int idx = blockIdx.x * 256 + threadIdx.x;   // b*N + i
    int b = idx >> 12;
    int i = idx & (N_BOX - 1);
    int rank = 0;
#pragma unroll
    for (int jg = 0; jg < JG; ++jg)
        rank += part[(b * JG + jg) * N_BOX + i];
    sboxes[b * N_BOX + rank] = boxes[idx];
    skeys[b * N_BOX + rank] = keyArr[idx];
}

// --- Kernel D: pull-based greedy NMS, one wave per image ---
// Kept list accumulates in LDS (<=163 entries before the >=100 break).
// Each 64-chunk: test against kept list (exact greedy "pull"), then resolve
// intra-chunk greedy serially via ballot/shfl (ascending bit order = greedy).
__global__ __launch_bounds__(64) void nms_kernel(
        const float4* __restrict__ sboxes, const float* __restrict__ skeys,
        float* __restrict__ out) {
    __shared__ float kx1[192], ky1[192], kx2[192], ky2[192], kar[192];
    int b = blockIdx.x;
    int l = threadIdx.x;
    const float4* sb = sboxes + (size_t)b * N_BOX;
    const float* sk = skeys + (size_t)b * N_BOX;

    int keptCnt = 0;                    // wave-uniform
    float4 nbx = sb[l];                 // prefetch chunk 0
    float nk = sk[l];
    for (int c = 0; c < 64; ++c) {
        float4 bx = nbx;
        float key = nk;
        if (c < 63) { nbx = sb[(c + 1) * 64 + l]; nk = sk[(c + 1) * 64 + l]; }
        float x1 = bx.x, y1 = bx.y, x2 = bx.z, y2 = bx.w;
        float ar;
        {
#pragma clang fp contract(off)
            ar = (x2 - x1) * (y2 - y1);
        }
        bool alive = (key != -INFINITY);
        // pull: suppress by any previously kept box (all finalized)
        for (int q = 0; q < keptCnt; ++q) {
            float v = iou_f(kx1[q], ky1[q], kx2[q], ky2[q], kar[q],
                            x1, y1, x2, y2, ar);
            if (v > IOUT) alive = false;
        }
        // intra-chunk greedy over surviving bits
        unsigned long long m = __ballot(alive);
        unsigned long long mm = m;
        while (mm) {
            int i = __ffsll(mm) - 1;
            float bx1 = __shfl(x1, i), by1 = __shfl(y1, i);
            float bx2 = __shfl(x2, i), by2 = __shfl(y2, i);
            float ba  = __shfl(ar, i);
            float v = iou_f(bx1, by1, bx2, by2, ba, x1, y1, x2, y2, ar);
            bool sup = (l > i) && (v > IOUT) && ((m >> l) & 1ull);
            unsigned long long sm = __ballot(sup);
            m &= ~sm;
            mm &= ~(1ull << i);
            mm &= m;
        }
        int cnt = __popcll(m);
        int pos = keptCnt + __popcll(m & ((1ull << l) - 1ull));
        if ((m >> l) & 1ull) {
            kx1[pos] = x1; ky1[pos] = y1; kx2[pos] = x2; ky2[pos] = y2; kar[pos] = ar;
        }
        keptCnt += cnt;
        __syncthreads();               // order LDS append vs next chunk's pull reads
        if (keptCnt >= MAXDET) break;
    }

    int tot = keptCnt < MAXDET ? keptCnt : MAXDET;
    float* ob = out + (size_t)b * MAXDET * 5;
    for (int r = l; r < MAXDET; r += 64) {
        float* row = ob + r * 5;
        if (r < tot) {
            row[0] = (float)b;
            row[1] = kx1[r]; row[2] = ky1[r]; row[3] = kx2[r]; row[4] = ky2[r];
        } else {
            row[0] = -1.0f;
            row[1] = 0.0f; row[2] = 0.0f; row[3] = 0.0f; row[4] = 0.0f;
        }
    }
}

extern "C" void kernel_launch(void* const* d_in, const int* in_sizes, int n_in,
                              void* d_out, int out_size, void* d_ws, size_t ws_size,
                              hipStream_t stream) {
    const float4* boxes = (const float4*)d_in[0];  // [16,4096,4] f32
    const float* scores = (const float*)d_in[1];   // [16,4096] f32
    float* out = (float*)d_out;                    // [16,100,5] f32

    // ws layout (2 MiB total):
    //   keyArr [0, 256K) | part u16 [256K, 768K) | sboxes [768K, 1792K) | skeys [1792K, 2048K)
    float* keyArr        = (float*)d_ws;
    unsigned short* part = (unsigned short*)((char*)d_ws + (size_t)262144);
    float4* sboxes       = (float4*)((char*)d_ws + (size_t)786432);
    float* skeys         = (float*)((char*)d_ws + (size_t)1835008);

    key_kernel<<<B_IMG * N_BOX / 256, 256, 0, stream>>>(boxes, scores, keyArr);
    partial_rank_kernel<<<B_IMG * IG * JG, 256, 0, stream>>>(keyArr, part);
    scatter_kernel<<<B_IMG * N_BOX / 256, 256, 0, stream>>>(boxes, keyArr, part, sboxes, skeys);
    nms_kernel<<<B_IMG, 64, 0, stream>>>(sboxes, skeys, out);
}

// Round 6
// 110.249 us; speedup vs baseline: 2.4210x; 1.2935x over previous
//
#include <hip/hip_runtime.h>
#include <math.h>

#define N_BOX 4096
#define B_IMG 16
#define MAXDET 100
#define MINSZ 25.0f
#define IOUT 0.3f
#define IG 16            // i-groups of 256 per image
#define JG 8             // j-groups of 512 per image
#define JW (N_BOX / JG)  // 512

// IoU with the reference's exact op order:
//   inter / (((ai + aj) - inter) + 1e-9)
// fp contract OFF so hipcc doesn't fuse wx*wy into the subtract (XLA doesn't).
__device__ __forceinline__ float iou_f(float ax1, float ay1, float ax2, float ay2, float aarea,
                                       float bx1, float by1, float bx2, float by2, float barea) {
#pragma clang fp contract(off)
    float lx = fmaxf(ax1, bx1);
    float ly = fmaxf(ay1, by1);
    float rx = fminf(ax2, bx2);
    float ry = fminf(ay2, by2);
    float wx = fmaxf(rx - lx, 0.0f);
    float wy = fmaxf(ry - ly, 0.0f);
    float inter = wx * wy;
    float denom = ((aarea + barea) - inter) + 1e-9f;
    return inter / denom;
}

// --- Kernel A: packed sort keys ---
// u = order-preserving uint of (valid ? score : -inf)  (no NaN / -0 in this data)
// C = (u << 12) | (4095 - i)  =>  stable-descending comparator == single u64 '>'
__global__ __launch_bounds__(256) void key_kernel(
        const float4* __restrict__ boxes, const float* __restrict__ scores,
        unsigned long long* __restrict__ ckey) {
    int idx = blockIdx.x * 256 + threadIdx.x;   // b*N + i
    float4 bx = boxes[idx];
    bool valid = ((bx.z - bx.x) >= MINSZ) && ((bx.w - bx.y) >= MINSZ);
    float k = valid ? scores[idx] : -INFINITY;
    unsigned u = __float_as_uint(k);
    u = (u & 0x80000000u) ? ~u : (u | 0x80000000u);
    int i = idx & (N_BOX - 1);
    ckey[idx] = ((unsigned long long)u << 12) | (unsigned long long)(N_BOX - 1 - i);
}

// --- Kernel B: partial stable ranks, 1 u64 compare per element ---
// grid: B_IMG*IG*JG = 2048 blocks x 256 threads -> 8 blocks/CU, 32 waves/CU.
__global__ __launch_bounds__(256) void partial_rank_kernel(
        const unsigned long long* __restrict__ ckey, unsigned short* __restrict__ part) {
    int blk = blockIdx.x;
    int jg = blk & (JG - 1);
    int ig = (blk >> 3) & (IG - 1);
    int b  = blk >> 7;                 // JG*IG = 128 blocks per image
    int t = threadIdx.x;
    int i = ig * 256 + t;
    unsigned long long ci = ckey[b * N_BOX + i];
    const unsigned long long* cj = ckey + b * N_BOX + jg * JW;  // wave-uniform scan
    int r = 0;
#pragma unroll 8
    for (int j = 0; j < JW; ++j)
        r += (cj[j] > ci) ? 1 : 0;
    part[(b * JG + jg) * N_BOX + i] = (unsigned short)r;
}

// --- Kernel C: sum partials -> rank; write inverse permutation (+valid bit) ---
__global__ __launch_bounds__(256) void scatter_kernel(
        const unsigned long long* __restrict__ ckey,
        const unsigned short* __restrict__ part,
        unsigned short* __restrict__ inv) {
    int idx = blockIdx.x * 256 + threadIdx.x;   // b*N + i
    int b = idx >> 12;
    int i = idx & (N_BOX - 1);
    int rank = 0;
#pragma unroll
    for (int jg = 0; jg < JG; ++jg)
        rank += part[(b * JG + jg) * N_BOX + i];
    unsigned valid = (unsigned)(ckey[idx] >> 43) & 1u;   // bit31 of u => score != -inf
    inv[b * N_BOX + rank] = (unsigned short)(i | (valid << 15));
}

// --- Kernel D: pull-based greedy NMS, one wave per image, gather via inv ---
__global__ __launch_bounds__(64) void nms_kernel(
        const float4* __restrict__ boxes, const unsigned short* __restrict__ inv,
        float* __restrict__ out) {
    __shared__ float kx1[192], ky1[192], kx2[192], ky2[192], kar[192];
    int b = blockIdx.x;
    int l = threadIdx.x;
    const float4* bb = boxes + (size_t)b * N_BOX;
    const unsigned short* iv = inv + (size_t)b * N_BOX;

    int keptCnt = 0;                    // wave-uniform
    unsigned short ni = iv[l];          // prefetch chunk 0
    float4 nbx = bb[ni & 0xFFFu];
    for (int c = 0; c < 64; ++c) {
        unsigned short e = ni;
        float4 bx = nbx;
        if (c < 63) { ni = iv[(c + 1) * 64 + l]; nbx = bb[ni & 0xFFFu]; }
        float x1 = bx.x, y1 = bx.y, x2 = bx.z, y2 = bx.w;
        float ar;
        {
#pragma clang fp contract(off)
            ar = (x2 - x1) * (y2 - y1);
        }
        bool alive = (e >> 15) != 0;
        // pull: suppress by any previously kept box (all finalized)
        for (int q = 0; q < keptCnt; ++q) {
            float v = iou_f(kx1[q], ky1[q], kx2[q], ky2[q], kar[q],
                            x1, y1, x2, y2, ar);
            if (v > IOUT) alive = false;
        }
        // intra-chunk greedy over surviving bits (ascending = greedy order)
        unsigned long long m = __ballot(alive);
        unsigned long long mm = m;
        while (mm) {
            int i = __ffsll(mm) - 1;
            float bx1 = __shfl(x1, i), by1 = __shfl(y1, i);
            float bx2 = __shfl(x2, i), by2 = __shfl(y2, i);
            float ba  = __shfl(ar, i);
            float v = iou_f(bx1, by1, bx2, by2, ba, x1, y1, x2, y2, ar);
            bool sup = (l > i) && (v > IOUT) && ((m >> l) & 1ull);
            unsigned long long sm = __ballot(sup);
            m &= ~sm;
            mm &= ~(1ull << i);
            mm &= m;
        }
        int cnt = __popcll(m);
        int pos = keptCnt + __popcll(m & ((1ull << l) - 1ull));
        if ((m >> l) & 1ull) {
            kx1[pos] = x1; ky1[pos] = y1; kx2[pos] = x2; ky2[pos] = y2; kar[pos] = ar;
        }
        keptCnt += cnt;
        __syncthreads();               // order LDS append vs next chunk's pull reads
        if (keptCnt >= MAXDET) break;
    }

    int tot = keptCnt < MAXDET ? keptCnt : MAXDET;
    float* ob = out + (size_t)b * MAXDET * 5;
    for (int r = l; r < MAXDET; r += 64) {
        float* row = ob + r * 5;
        if (r < tot) {
            row[0] = (float)b;
            row[1] = kx1[r]; row[2] = ky1[r]; row[3] = kx2[r]; row[4] = ky2[r];
        } else {
            row[0] = -1.0f;
            row[1] = 0.0f; row[2] = 0.0f; row[3] = 0.0f; row[4] = 0.0f;
        }
    }
}

extern "C" void kernel_launch(void* const* d_in, const int* in_sizes, int n_in,
                              void* d_out, int out_size, void* d_ws, size_t ws_size,
                              hipStream_t stream) {
    const float4* boxes = (const float4*)d_in[0];  // [16,4096,4] f32
    const float* scores = (const float*)d_in[1];   // [16,4096] f32
    float* out = (float*)d_out;                    // [16,100,5] f32

    // ws layout (1.625 MiB):
    //   ckey u64 [0, 512K) | part u16 [512K, 1536K) | inv u16 [1536K, 1664K)
    unsigned long long* ckey = (unsigned long long*)d_ws;
    unsigned short* part     = (unsigned short*)((char*)d_ws + (size_t)524288);
    unsigned short* inv      = (unsigned short*)((char*)d_ws + (size_t)1572864);

    key_kernel<<<B_IMG * N_BOX / 256, 256, 0, stream>>>(boxes, scores, ckey);
    partial_rank_kernel<<<B_IMG * IG * JG, 256, 0, stream>>>(ckey, part);
    scatter_kernel<<<B_IMG * N_BOX / 256, 256, 0, stream>>>(ckey, part, inv);
    nms_kernel<<<B_IMG, 64, 0, stream>>>(boxes, inv, out);
}